// Round 13
// baseline (242.834 us; speedup 1.0000x reference)
//
#include <hip/hip_runtime.h>
#include <math.h>

typedef unsigned short u16;
typedef __attribute__((ext_vector_type(8))) short    bf16x8;
typedef __attribute__((ext_vector_type(8))) unsigned short u16x8;
typedef __attribute__((ext_vector_type(4))) float    f32x4;

// Problem constants
#define NB   32        // batch
#define NC   256       // in channels
#define NO   256       // out channels
#define NH   56
#define NW   56
#define NP   3136      // H*W
#define NE   8
#define NID  64
#define HP   58        // padded rows
#define WP   64        // padded row width (aligned)

// Workspace layout (bytes)
#define WMIX_OFF   0                    // u16 [32][9][256][256] = 37,748,736 B
#define XPT_OFF    37748736             // u16 [32][58][64][256] = 60,817,408 B
#define POOL_OFF   98566144             // f32 [32][256]
#define RBUF_OFF   98598912             // f32 [32][8]

__device__ __forceinline__ u16 f2bf(float f) {
    unsigned u = __float_as_uint(f);
    unsigned r = (u + 0x7FFFu + ((u >> 16) & 1u)) >> 16;   // RNE
    return (u16)r;
}

__device__ __forceinline__ void gl_lds16(const void* g, void* l) {
    __builtin_amdgcn_global_load_lds(
        (const __attribute__((address_space(1))) unsigned int*)g,
        (__attribute__((address_space(3))) unsigned int*)l, 16, 0, 0);
}

#define SBAR() __builtin_amdgcn_sched_barrier(0);
// counted wait (perf hint only; correctness is register-dep guaranteed)
#define VM_WAIT(N) { asm volatile("s_waitcnt vmcnt(" #N ")" ::: "memory"); \
                     __builtin_amdgcn_sched_barrier(0); }

// ---------------------------------------------------------------- kernel 0
// Zero pooled accumulators + the two border rows (h'=0,57) of xpadT.
__global__ __launch_bounds__(256) void zero_k(float* __restrict__ pooled,
                                              u16* __restrict__ xpadT) {
    int b = blockIdx.x, t = threadIdx.x;
    pooled[b * 256 + t] = 0.0f;
    u16x8 z = {0, 0, 0, 0, 0, 0, 0, 0};
    u16* r0 = xpadT + ((size_t)(b * HP + 0)) * WP * NC;
    u16* r1 = xpadT + ((size_t)(b * HP + 57)) * WP * NC;
    #pragma unroll
    for (int i = 0; i < 8; ++i) {
        *(u16x8*)&r0[(i * 256 + t) * 8] = z;
        *(u16x8*)&r1[(i * 256 + t) * 8] = z;
    }
}

// ---------------------------------------------------------------- kernel 1
// One block per (b,h): NCHW fp32 -> padded NHWC bf16 row transpose + pooling
// partial sums (computed from the LDS tile; no shuffles).
// LDS tile: u16 [64 w][32 slots of 8c], physical slot = s ^ (w>>2).
__global__ __launch_bounds__(256) void transpose_pool_k(const float* __restrict__ x,
                                                        u16* __restrict__ xpadT,
                                                        float* __restrict__ pooled) {
    __shared__ u16 tile[64 * 256];          // 32 KB
    int b = blockIdx.x / 56;
    int h = blockIdx.x % 56;
    int t = threadIdx.x;

    // ---- write phase: coalesced float4 reads along w
    int w4 = t & 15, c_sub = t >> 4;        // w4: 0..13 valid (56 w), c_sub: 0..15
    if (w4 < 14) {
        const float* xp = x + ((size_t)b * NC + c_sub) * NP + (size_t)h * NW + w4 * 4;
        #pragma unroll
        for (int it = 0; it < 16; ++it) {
            int c = it * 16 + c_sub;
            f32x4 v = *(const f32x4*)(xp + (size_t)it * 16 * NP);
            int key = w4;                    // (w>>2) for all 4 written rows
            int base = ((c >> 3) ^ key) * 8 + (c & 7);
            #pragma unroll
            for (int i = 0; i < 4; ++i)
                tile[(w4 * 4 + i) * 256 + base] = f2bf(v[i]);
        }
    }
    __syncthreads();

    // ---- global write phase: u16x8 along c, 1 KB/wave
    {
        int c8 = t & 31, whi = t >> 5;       // whi: 0..7
        u16* orow = xpadT + ((size_t)(b * HP + h + 1)) * WP * NC;
        #pragma unroll
        for (int j = 0; j < 8; ++j) {
            int wp = whi * 8 + j;
            u16x8 v = {0, 0, 0, 0, 0, 0, 0, 0};
            if (wp >= 1 && wp <= 56) {
                int w = wp - 1;
                v = *(const u16x8*)&tile[w * 256 + ((c8 ^ (w >> 2)) * 8)];
            }
            *(u16x8*)&orow[wp * NC + c8 * 8] = v;
        }
    }

    // ---- pool phase: per-thread channel sum over the 56 w of this row
    {
        int c = t;
        int s = c >> 3, sub = c & 7;
        float sum = 0.0f;
        #pragma unroll
        for (int w = 0; w < 56; ++w) {
            u16 u = tile[w * 256 + ((s ^ (w >> 2)) * 8) + sub];
            sum += __uint_as_float(((unsigned)u) << 16);
        }
        atomicAdd(&pooled[b * 256 + c], sum);
    }
}

// ---------------------------------------------------------------- kernel 2
// routing: rt = (pooled/3136) @ proj_w^T + proj_b ; sigmoid ; avgpool(8) -> r[32][8]
__global__ __launch_bounds__(64) void routing(const float* __restrict__ pooled,
                                              const float* __restrict__ proj_w,
                                              const float* __restrict__ proj_b,
                                              float* __restrict__ r) {
    __shared__ float ps[256];
    __shared__ float sg[64];
    int b = blockIdx.x, j = threadIdx.x;
    for (int i = j; i < 256; i += 64) ps[i] = pooled[b * NC + i] * (1.0f / 3136.0f);
    __syncthreads();
    float acc = proj_b[j];
    for (int c = 0; c < 256; ++c) acc += ps[c] * proj_w[j * NC + c];
    sg[j] = 1.0f / (1.0f + expf(-acc));
    __syncthreads();
    if (j < NE) {
        float s = 0.0f;
        #pragma unroll
        for (int q = 0; q < 8; ++q) s += sg[j * 8 + q];
        r[b * NE + j] = s * 0.125f;
    }
}

// ---------------------------------------------------------------- kernel 3
// wmix[b][kk][o][c] = bf16( sum_e r[b][e] * expert_w[e][o][c][kk] )
__global__ __launch_bounds__(256) void mix_w(const float* __restrict__ expert_w,
                                             const float* __restrict__ r,
                                             u16* __restrict__ wmix) {
    __shared__ float lr[256];
    int o = blockIdx.x, c = threadIdx.x;
    lr[c] = r[c];                               // 32*8 = 256
    __syncthreads();
    float w[8][9];
    #pragma unroll
    for (int e = 0; e < 8; ++e) {
        const float* p = expert_w + ((size_t)((e * NO + o) * NC + c)) * 9;
        #pragma unroll
        for (int kk = 0; kk < 9; ++kk) w[e][kk] = p[kk];
    }
    for (int b = 0; b < NB; ++b) {
        float acc[9] = {0, 0, 0, 0, 0, 0, 0, 0, 0};
        #pragma unroll
        for (int e = 0; e < 8; ++e) {
            float rv = lr[b * 8 + e];
            #pragma unroll
            for (int kk = 0; kk < 9; ++kk) acc[kk] += rv * w[e][kk];
        }
        #pragma unroll
        for (int kk = 0; kk < 9; ++kk)
            wmix[((size_t)((b * 9 + kk) * NO + o)) * NC + c] = f2bf(acc[kk]);
    }
}

// ---------------------------------------------------------------- kernel 4
// Implicit-GEMM conv. 256 threads (4 waves). Per block: b, FULL o=256,
// p-tile 112. Wave w owns o-rows [w*64, w*64+64): acc[4][7] (112 AGPR),
// B-frag reused across 4 mi (LDS reads: 14 per 56 MFMAs).
// A (weights): DIRECT global->VGPR, pipelined at HALF-TAP (ks) granularity:
//   abufA serves ks=0 halves, abufB ks=1 halves. Each half: VM_WAIT(4) ->
//   28 MFMAs -> issue next tap's same-ks 4 frags into the SAME buffer
//   (WAR-ordered after the consuming MFMAs; SBAR pins it). Steady state
//   8 loads in flight, wait leaves 4 (T4, never 0 mid-loop).
// __launch_bounds__(256, 2): occupancy model (r10-r12): waves/SIMD =
//   floor(512 / (VGPR + AGPR)). r12 at arg2=1 let the allocator take 156
//   VGPR + 112 AGPR = 268 > 256 -> 1 wave/SIMD (occ 10%). True live VGPR
//   is ~70-100 (abuf 32 + addressing); arg2=2 caps VGPR at 144 which fits
//   without spill (unlike r10, whose abuf-64 live set overflowed the cap).
//   Tripwire: WRITE_SIZE must stay ~100 MB.
// B (image): 4 padded rows [256x64] staged once per c0 via global_load_lds,
//   XOR-swizzled via pre-swizzled global source (2 barriers per c0).
// Grid 896 = 8 XCD x 112, bijective swizzle: each XCD owns 4 consecutive b.
__global__ __launch_bounds__(256, 2) void conv_k(const u16* __restrict__ wmix,
                                                 const u16* __restrict__ xpadT,
                                                 float* __restrict__ out) {
    __shared__ u16 Bs[256 * 64];       // 32 KB (the only LDS)
    char* Bsc = (char*)Bs;

    int tid  = threadIdx.x;
    int lane = tid & 63, wid = tid >> 6;     // wid 0..3
    int ln = lane & 15, hi = lane >> 4;

    int bid = blockIdx.x;
    int logical = (bid & 7) * 112 + (bid >> 3);
    int b  = logical / 28;
    int nt = logical % 28;
    int h0 = nt * 2;          // padded image row base
    int p0 = nt * 112;

    const u16* apane = wmix + (size_t)b * 9 * 65536;                 // + kk*65536 + o*256 + c
    const u16* xbase = xpadT + ((size_t)(b * HP + h0)) * WP * NC;    // + rw*256 + c

    // per-lane A base: row = wid*64 + ln, k-slice offset hi*8 elements
    const u16* alane = apane + (size_t)(wid * 64 + ln) * 256 + hi * 8;

    // ---- B staging: thread t covers rows t3+i*32, slot t7 (pre-swizzled src)
    int t3 = tid >> 3, t7 = tid & 7;
    int bstg_src = t3 * 256 + ((t7 ^ (t3 & 7)) * 8);   // elements
    int bstg_dst = tid * 16;                            // bytes, linear
    #define STAGE_B(C0) {                                                   \
        _Pragma("unroll")                                                   \
        for (int i = 0; i < 8; ++i)                                         \
            gl_lds16(xbase + (C0) + bstg_src + i * 8192,                    \
                     Bsc + bstg_dst + i * 4096);                            \
    }

    // A half-tap fragment registers: [mi], ks0 -> abufA, ks1 -> abufB
    bf16x8 abufA[4], abufB[4];
    #define ISSUE_H(KK, KS, C0, BUF) {                                      \
        const u16* ap_ = alane + (KK) * 65536 + (C0) + (KS) * 32;           \
        BUF[0] = *(const bf16x8*)(ap_);                                     \
        BUF[1] = *(const bf16x8*)(ap_ + 4096);                              \
        BUF[2] = *(const bf16x8*)(ap_ + 8192);                              \
        BUF[3] = *(const bf16x8*)(ap_ + 12288);                             \
    }

    // accumulators: 4 mi x 7 ni
    f32x4 acc[4][7];
    #pragma unroll
    for (int mi = 0; mi < 4; ++mi)
        #pragma unroll
        for (int ni = 0; ni < 7; ++ni) acc[mi][ni] = (f32x4){0.f, 0.f, 0.f, 0.f};

    // per-lane B row bases: p = ni*16 + ln ; rw = hr*64 + wv + 1
    int rwbase[7];
    #pragma unroll
    for (int ni = 0; ni < 7; ++ni) {
        int p  = ni * 16 + ln;
        int hr = (p >= 56) ? 1 : 0;
        int wv = p - hr * 56;
        rwbase[ni] = hr * 64 + wv + 1;
    }

    #define HALF(KK, KS, BUF) {                                             \
        const int dh = (KK) / 3, kw = (KK) % 3;                             \
        _Pragma("unroll")                                                   \
        for (int ni = 0; ni < 7; ++ni) {                                    \
            int rw   = rwbase[ni] + dh * 64 + kw - 1;                       \
            int boff = rw * 128 + (((((KS) << 2) + hi) ^ (rw & 7)) << 4);   \
            bf16x8 bv = *(const bf16x8*)(Bsc + boff);                       \
            acc[0][ni] = __builtin_amdgcn_mfma_f32_16x16x32_bf16(BUF[0], bv, acc[0][ni], 0, 0, 0); \
            acc[1][ni] = __builtin_amdgcn_mfma_f32_16x16x32_bf16(BUF[1], bv, acc[1][ni], 0, 0, 0); \
            acc[2][ni] = __builtin_amdgcn_mfma_f32_16x16x32_bf16(BUF[2], bv, acc[2][ni], 0, 0, 0); \
            acc[3][ni] = __builtin_amdgcn_mfma_f32_16x16x32_bf16(BUF[3], bv, acc[3][ni], 0, 0, 0); \
        }                                                                   \
    }

    // one tap: two pipelined halves; NKK/NC0 = source of the prefetch
    #define TAP(KK, C0, NKK, NC0) {                                         \
        VM_WAIT(4) HALF(KK, 0, abufA) ISSUE_H(NKK, 0, NC0, abufA) SBAR()    \
        VM_WAIT(4) HALF(KK, 1, abufB) ISSUE_H(NKK, 1, NC0, abufB) SBAR()    \
    }

    #define CHUNK(C0, LAST) {                                               \
        TAP(0, C0, 1, C0) TAP(1, C0, 2, C0) TAP(2, C0, 3, C0)               \
        TAP(3, C0, 4, C0) TAP(4, C0, 5, C0) TAP(5, C0, 6, C0)               \
        TAP(6, C0, 7, C0) TAP(7, C0, 8, C0)                                 \
        if (LAST) {                                                         \
            VM_WAIT(4) HALF(8, 0, abufA)                                    \
            VM_WAIT(0) HALF(8, 1, abufB)                                    \
        } else {                                                            \
            TAP(8, C0, 0, (C0) + 64)                                        \
            __syncthreads();                                                \
            STAGE_B((C0) + 64)                                              \
            __syncthreads();                                                \
        }                                                                   \
    }

    // prologue: B(c0=0) staged, A(tap0 both halves) in flight -> barrier drains
    STAGE_B(0)
    ISSUE_H(0, 0, 0, abufA)
    ISSUE_H(0, 1, 0, abufB)
    __syncthreads();

    CHUNK(0, 0)
    CHUNK(64, 0)
    CHUNK(128, 0)
    CHUNK(192, 1)

    #undef CHUNK
    #undef TAP
    #undef HALF
    #undef ISSUE_H
    #undef STAGE_B

    // epilogue: D col = lane&15 (p), row = (lane>>4)*4 + reg (o)
    float* op = out + ((size_t)(b * NO + wid * 64)) * NP + p0;
    #pragma unroll
    for (int mi = 0; mi < 4; ++mi)
        #pragma unroll
        for (int ni = 0; ni < 7; ++ni) {
            f32x4 v = acc[mi][ni];
            int col = ni * 16 + ln;
            #pragma unroll
            for (int rg = 0; rg < 4; ++rg) {
                int row = mi * 16 + hi * 4 + rg;
                op[(size_t)row * NP + col] = v[rg];
            }
        }
}

// ---------------------------------------------------------------- launch
extern "C" void kernel_launch(void* const* d_in, const int* in_sizes, int n_in,
                              void* d_out, int out_size, void* d_ws, size_t ws_size,
                              hipStream_t stream) {
    (void)in_sizes; (void)n_in; (void)out_size; (void)ws_size;
    const float* x        = (const float*)d_in[0];
    const float* proj_w   = (const float*)d_in[1];
    const float* proj_b   = (const float*)d_in[2];
    const float* expert_w = (const float*)d_in[3];
    float* out = (float*)d_out;
    char*  ws  = (char*)d_ws;

    u16*   wmix   = (u16*)(ws + WMIX_OFF);
    u16*   xpadT  = (u16*)(ws + XPT_OFF);
    float* pooled = (float*)(ws + POOL_OFF);
    float* rbuf   = (float*)(ws + RBUF_OFF);

    zero_k<<<dim3(32), dim3(256), 0, stream>>>(pooled, xpadT);
    transpose_pool_k<<<dim3(32 * 56), dim3(256), 0, stream>>>(x, xpadT, pooled);
    routing<<<dim3(32), dim3(64), 0, stream>>>(pooled, proj_w, proj_b, rbuf);
    mix_w<<<dim3(256), dim3(256), 0, stream>>>(expert_w, rbuf, wmix);
    conv_k<<<dim3(32 * 28), dim3(256), 0, stream>>>(wmix, xpadT, out);
}

// Round 14
// 204.106 us; speedup vs baseline: 1.1897x; 1.1897x over previous
//
#include <hip/hip_runtime.h>
#include <math.h>

typedef unsigned short u16;
typedef __attribute__((ext_vector_type(8))) short    bf16x8;
typedef __attribute__((ext_vector_type(8))) unsigned short u16x8;
typedef __attribute__((ext_vector_type(4))) float    f32x4;

// Problem constants
#define NB   32        // batch
#define NC   256       // in channels
#define NO   256       // out channels
#define NH   56
#define NW   56
#define NP   3136      // H*W
#define NE   8
#define NID  64
#define HP   58        // padded rows
#define WP   64        // padded row width (aligned)

// Workspace layout (bytes)
#define WMIX_OFF   0                    // u16 [32][9][256][256] = 37,748,736 B
#define XPT_OFF    37748736             // u16 [32][58][64][256] = 60,817,408 B
#define POOL_OFF   98566144             // f32 [32][256]
#define RBUF_OFF   98598912             // f32 [32][8]

__device__ __forceinline__ u16 f2bf(float f) {
    unsigned u = __float_as_uint(f);
    unsigned r = (u + 0x7FFFu + ((u >> 16) & 1u)) >> 16;   // RNE
    return (u16)r;
}

__device__ __forceinline__ void gl_lds16(const void* g, void* l) {
    __builtin_amdgcn_global_load_lds(
        (const __attribute__((address_space(1))) unsigned int*)g,
        (__attribute__((address_space(3))) unsigned int*)l, 16, 0, 0);
}

// wave-local counted wait; memory clobber orders the following ds_reads,
// sched_barrier pins the schedule (rule #18).
#define VM_WAIT(N) { asm volatile("s_waitcnt vmcnt(" #N ")" ::: "memory"); \
                     __builtin_amdgcn_sched_barrier(0); }

// ---------------------------------------------------------------- kernel 0
// Zero pooled accumulators + the two border rows (h'=0,57) of xpadT.
__global__ __launch_bounds__(256) void zero_k(float* __restrict__ pooled,
                                              u16* __restrict__ xpadT) {
    int b = blockIdx.x, t = threadIdx.x;
    pooled[b * 256 + t] = 0.0f;
    u16x8 z = {0, 0, 0, 0, 0, 0, 0, 0};
    u16* r0 = xpadT + ((size_t)(b * HP + 0)) * WP * NC;
    u16* r1 = xpadT + ((size_t)(b * HP + 57)) * WP * NC;
    #pragma unroll
    for (int i = 0; i < 8; ++i) {
        *(u16x8*)&r0[(i * 256 + t) * 8] = z;
        *(u16x8*)&r1[(i * 256 + t) * 8] = z;
    }
}

// ---------------------------------------------------------------- kernel 1
// One block per (b,h): NCHW fp32 -> padded NHWC bf16 row transpose + pooling
// partial sums (computed from the LDS tile; no shuffles).
// LDS tile: u16 [64 w][32 slots of 8c], physical slot = s ^ (w>>2).
__global__ __launch_bounds__(256) void transpose_pool_k(const float* __restrict__ x,
                                                        u16* __restrict__ xpadT,
                                                        float* __restrict__ pooled) {
    __shared__ u16 tile[64 * 256];          // 32 KB
    int b = blockIdx.x / 56;
    int h = blockIdx.x % 56;
    int t = threadIdx.x;

    // ---- write phase: coalesced float4 reads along w
    int w4 = t & 15, c_sub = t >> 4;        // w4: 0..13 valid (56 w), c_sub: 0..15
    if (w4 < 14) {
        const float* xp = x + ((size_t)b * NC + c_sub) * NP + (size_t)h * NW + w4 * 4;
        #pragma unroll
        for (int it = 0; it < 16; ++it) {
            int c = it * 16 + c_sub;
            f32x4 v = *(const f32x4*)(xp + (size_t)it * 16 * NP);
            int key = w4;                    // (w>>2) for all 4 written rows
            int base = ((c >> 3) ^ key) * 8 + (c & 7);
            #pragma unroll
            for (int i = 0; i < 4; ++i)
                tile[(w4 * 4 + i) * 256 + base] = f2bf(v[i]);
        }
    }
    __syncthreads();

    // ---- global write phase: u16x8 along c, 1 KB/wave
    {
        int c8 = t & 31, whi = t >> 5;       // whi: 0..7
        u16* orow = xpadT + ((size_t)(b * HP + h + 1)) * WP * NC;
        #pragma unroll
        for (int j = 0; j < 8; ++j) {
            int wp = whi * 8 + j;
            u16x8 v = {0, 0, 0, 0, 0, 0, 0, 0};
            if (wp >= 1 && wp <= 56) {
                int w = wp - 1;
                v = *(const u16x8*)&tile[w * 256 + ((c8 ^ (w >> 2)) * 8)];
            }
            *(u16x8*)&orow[wp * NC + c8 * 8] = v;
        }
    }

    // ---- pool phase: per-thread channel sum over the 56 w of this row
    {
        int c = t;
        int s = c >> 3, sub = c & 7;
        float sum = 0.0f;
        #pragma unroll
        for (int w = 0; w < 56; ++w) {
            u16 u = tile[w * 256 + ((s ^ (w >> 2)) * 8) + sub];
            sum += __uint_as_float(((unsigned)u) << 16);
        }
        atomicAdd(&pooled[b * 256 + c], sum);
    }
}

// ---------------------------------------------------------------- kernel 2
// routing: rt = (pooled/3136) @ proj_w^T + proj_b ; sigmoid ; avgpool(8) -> r[32][8]
__global__ __launch_bounds__(64) void routing(const float* __restrict__ pooled,
                                              const float* __restrict__ proj_w,
                                              const float* __restrict__ proj_b,
                                              float* __restrict__ r) {
    __shared__ float ps[256];
    __shared__ float sg[64];
    int b = blockIdx.x, j = threadIdx.x;
    for (int i = j; i < 256; i += 64) ps[i] = pooled[b * NC + i] * (1.0f / 3136.0f);
    __syncthreads();
    float acc = proj_b[j];
    for (int c = 0; c < 256; ++c) acc += ps[c] * proj_w[j * NC + c];
    sg[j] = 1.0f / (1.0f + expf(-acc));
    __syncthreads();
    if (j < NE) {
        float s = 0.0f;
        #pragma unroll
        for (int q = 0; q < 8; ++q) s += sg[j * 8 + q];
        r[b * NE + j] = s * 0.125f;
    }
}

// ---------------------------------------------------------------- kernel 3
// wmix[b][kk][o][c] = bf16( sum_e r[b][e] * expert_w[e][o][c][kk] )
__global__ __launch_bounds__(256) void mix_w(const float* __restrict__ expert_w,
                                             const float* __restrict__ r,
                                             u16* __restrict__ wmix) {
    __shared__ float lr[256];
    int o = blockIdx.x, c = threadIdx.x;
    lr[c] = r[c];                               // 32*8 = 256
    __syncthreads();
    float w[8][9];
    #pragma unroll
    for (int e = 0; e < 8; ++e) {
        const float* p = expert_w + ((size_t)((e * NO + o) * NC + c)) * 9;
        #pragma unroll
        for (int kk = 0; kk < 9; ++kk) w[e][kk] = p[kk];
    }
    for (int b = 0; b < NB; ++b) {
        float acc[9] = {0, 0, 0, 0, 0, 0, 0, 0, 0};
        #pragma unroll
        for (int e = 0; e < 8; ++e) {
            float rv = lr[b * 8 + e];
            #pragma unroll
            for (int kk = 0; kk < 9; ++kk) acc[kk] += rv * w[e][kk];
        }
        #pragma unroll
        for (int kk = 0; kk < 9; ++kk)
            wmix[((size_t)((b * 9 + kk) * NO + o)) * NC + c] = f2bf(acc[kk]);
    }
}

// ---------------------------------------------------------------- kernel 4
// Implicit-GEMM conv -- r8 structure with BK=32 for occupancy.
// 256 threads (4 waves). Per block: b, o-tile 128, p-tile 112.
// K = 8 c0-chunks of 32 x 9 taps. Wave owns 32 o-rows: acc[2][7] (56 AGPR).
// A (weights): WAVE-PRIVATE LDS slices (2 KB/tap), 3-buffer pipeline staged
//   2 taps ahead via global_load_lds (2 loads/stage); counted VM_WAIT(4)
//   leaves the 2 newer stages in flight (T4, never 0 mid-loop).
// B (image): 4 padded rows [256 rw][32 c] (16 KB) staged once per c0
//   (2 barriers/c0, the only block-wide syncs).
// LDS swizzle (both tiles): rows are 64 B; pack 2 rows per 128 B line,
//   8 x 16B slots; physical slot = ((row&1)*4 + g) ^ ((line)&7). Staged via
//   pre-swizzled GLOBAL source + linear LDS dst (m173); reads apply the same
//   XOR. Per wave access each line's 8 slots are read exactly once ->
//   conflict-free. Total LDS 40 KB; regs (~166 unified) bind occupancy at
//   3 waves/SIMD (r8 was LDS-capped at 2).
// Grid 1792 = 8 XCD x 224, bijective swizzle: each XCD owns 4 consecutive b.
__global__ __launch_bounds__(256, 2) void conv_k(const u16* __restrict__ wmix,
                                                 const u16* __restrict__ xpadT,
                                                 float* __restrict__ out) {
    __shared__ u16 Bs[256 * 32];       // 16 KB
    __shared__ u16 As[3 * 128 * 32];   // 24 KB: [buf][wave slice 32r][32 c]
    char* Bsc = (char*)Bs;
    char* Asc = (char*)As;

    int tid  = threadIdx.x;
    int lane = tid & 63, wid = tid >> 6;     // wid 0..3
    int ln = lane & 15, hi = lane >> 4;

    int bid = blockIdx.x;
    int logical = (bid & 7) * 224 + (bid >> 3);
    int b   = logical / 56;
    int rem = logical % 56;
    int mt  = rem / 28, nt = rem % 28;
    int obase = mt * 128;
    int h0 = nt * 2;          // padded image row base
    int p0 = nt * 112;

    const u16* apane = wmix + (size_t)b * 9 * 65536 + (size_t)obase * 256;
    const u16* xbase = xpadT + ((size_t)(b * HP + h0)) * WP * NC;

    // ---- B staging: 16 KB = 128 lines x 128 B; thread t covers line
    // (t>>3)+i*32, slot t&7; source row/group decoded from the swizzle.
    int bl = tid >> 3, bs_ = tid & 7;
    #define STAGE_B(C0) {                                                   \
        _Pragma("unroll")                                                   \
        for (int i = 0; i < 4; ++i) {                                       \
            int ln_i = bl + i * 32;                                         \
            int sp   = bs_ ^ (ln_i & 7);                                    \
            int rw   = ln_i * 2 + (sp >> 2);                                \
            int g    = sp & 3;                                              \
            gl_lds16(xbase + (size_t)rw * 256 + (C0) + g * 8,               \
                     Bsc + tid * 16 + i * 4096);                            \
        }                                                                   \
    }

    // ---- A staging (wave-private, 2 KB = 16 lines): lane covers line
    // (lane>>3)+i*8, slot lane&7.
    int al = lane >> 3, as_ = lane & 7;
    #define STAGE_A(KK, C0, BUF) {                                          \
        _Pragma("unroll")                                                   \
        for (int i = 0; i < 2; ++i) {                                       \
            int ln_i = al + i * 8;                                          \
            int sp   = as_ ^ (ln_i & 7);                                    \
            int row  = ln_i * 2 + (sp >> 2);                                \
            int g    = sp & 3;                                              \
            gl_lds16(apane + (KK) * 65536 + (size_t)(wid * 32 + row) * 256  \
                         + (C0) + g * 8,                                    \
                     Asc + (BUF) * 8192 + wid * 2048 + lane * 16 + i * 1024); \
        }                                                                   \
    }

    // accumulators
    f32x4 acc[2][7];
    #pragma unroll
    for (int mi = 0; mi < 2; ++mi)
        #pragma unroll
        for (int ni = 0; ni < 7; ++ni) acc[mi][ni] = (f32x4){0.f, 0.f, 0.f, 0.f};

    // per-lane B row bases: p = ni*16 + ln ; rw = hr*64 + wv + 1
    int rwbase[7];
    #pragma unroll
    for (int ni = 0; ni < 7; ++ni) {
        int p  = ni * 16 + ln;
        int hr = (p >= 56) ? 1 : 0;
        int wv = p - hr * 56;
        rwbase[ni] = hr * 64 + wv + 1;
    }
    // A fragment byte offsets inside a buffer: row = mi*16+ln, k-group hi
    int aoffc[2];
    #pragma unroll
    for (int mi = 0; mi < 2; ++mi) {
        int row = mi * 16 + ln;
        aoffc[mi] = wid * 2048 + (row >> 1) * 128 +
                    (((((row & 1) << 2) + hi) ^ ((row >> 1) & 7)) << 4);
    }

    #define TAP(KK, BUF) {                                                  \
        const int dh = (KK) / 3, kw = (KK) % 3;                             \
        bf16x8 a0 = *(const bf16x8*)(Asc + (BUF) * 8192 + aoffc[0]);        \
        bf16x8 a1 = *(const bf16x8*)(Asc + (BUF) * 8192 + aoffc[1]);        \
        _Pragma("unroll")                                                   \
        for (int ni = 0; ni < 7; ++ni) {                                    \
            int rw   = rwbase[ni] + dh * 64 + kw - 1;                       \
            int boff = (rw >> 1) * 128 +                                    \
                       (((((rw & 1) << 2) + hi) ^ ((rw >> 1) & 7)) << 4);   \
            bf16x8 bv = *(const bf16x8*)(Bsc + boff);                       \
            acc[0][ni] = __builtin_amdgcn_mfma_f32_16x16x32_bf16(a0, bv, acc[0][ni], 0, 0, 0); \
            acc[1][ni] = __builtin_amdgcn_mfma_f32_16x16x32_bf16(a1, bv, acc[1][ni], 0, 0, 0); \
        }                                                                   \
    }

    // prologue: B(c0=0) + A taps 0,1
    STAGE_B(0)
    STAGE_A(0, 0, 0)
    STAGE_A(1, 0, 1)
    __syncthreads();                         // drains everything

    for (int c0 = 0; c0 < 256; c0 += 32) {
        #pragma unroll
        for (int kk = 0; kk < 9; ++kk) {
            const int cur = kk % 3;
            const int nxt = (kk + 2) % 3;
            if (kk < 7) {
                STAGE_A(kk + 2, c0, nxt)
                VM_WAIT(4)
            } else if (kk == 7) {
                if (c0 < 224) { STAGE_A(0, c0 + 32, nxt) VM_WAIT(4) }
                else          { VM_WAIT(2) }
            } else {            // kk == 8
                if (c0 < 224) { STAGE_A(1, c0 + 32, nxt) VM_WAIT(4) }
                else          { VM_WAIT(0) }
            }
            TAP(kk, cur)
        }
        if (c0 < 224) {
            __syncthreads();                 // all waves done reading Bs;
                                             // also drains rolled A prefetches
            STAGE_B(c0 + 32)
            __syncthreads();                 // publish B(next c0)
        }
    }
    #undef TAP
    #undef STAGE_A
    #undef STAGE_B

    // epilogue: D col = lane&15 (p), row = (lane>>4)*4 + reg (o)
    float* op = out + ((size_t)(b * NO + obase + wid * 32)) * NP + p0;
    #pragma unroll
    for (int mi = 0; mi < 2; ++mi)
        #pragma unroll
        for (int ni = 0; ni < 7; ++ni) {
            f32x4 v = acc[mi][ni];
            int col = ni * 16 + ln;
            #pragma unroll
            for (int rg = 0; rg < 4; ++rg) {
                int row = mi * 16 + hi * 4 + rg;
                op[(size_t)row * NP + col] = v[rg];
            }
        }
}

// ---------------------------------------------------------------- launch
extern "C" void kernel_launch(void* const* d_in, const int* in_sizes, int n_in,
                              void* d_out, int out_size, void* d_ws, size_t ws_size,
                              hipStream_t stream) {
    (void)in_sizes; (void)n_in; (void)out_size; (void)ws_size;
    const float* x        = (const float*)d_in[0];
    const float* proj_w   = (const float*)d_in[1];
    const float* proj_b   = (const float*)d_in[2];
    const float* expert_w = (const float*)d_in[3];
    float* out = (float*)d_out;
    char*  ws  = (char*)d_ws;

    u16*   wmix   = (u16*)(ws + WMIX_OFF);
    u16*   xpadT  = (u16*)(ws + XPT_OFF);
    float* pooled = (float*)(ws + POOL_OFF);
    float* rbuf   = (float*)(ws + RBUF_OFF);

    zero_k<<<dim3(32), dim3(256), 0, stream>>>(pooled, xpadT);
    transpose_pool_k<<<dim3(32 * 56), dim3(256), 0, stream>>>(x, xpadT, pooled);
    routing<<<dim3(32), dim3(64), 0, stream>>>(pooled, proj_w, proj_b, rbuf);
    mix_w<<<dim3(256), dim3(256), 0, stream>>>(expert_w, rbuf, wmix);
    conv_k<<<dim3(32 * 56), dim3(256), 0, stream>>>(wmix, xpadT, out);
}